// Round 13
// baseline (60.289 us; speedup 1.0000x reference)
//
#include <hip/hip_runtime.h>

// Adaptive mean thresholding: out = (x > mean11x11(x) - 2) ? 0 : 255, replicate border.
// BIT-EXACT contract (verified absmax=0.0 rounds 3-12): vertical 11-tap f32 FMA
// chain (ascending row order, weight (float)(1.0/11.0)), rounded to f32; then
// horizontal 11-tap f32 FMA chain (ascending col order); thresh = m - 2.0f;
// decision x > thresh. Replicate-border mv values are bitwise duplicates of the
// edge col's chain (synthesized by duplication, never recomputed).
//
// R13: full 16 B/lane memory path (the m13 6.29 TB/s ceiling is a dwordx4
// pattern; all prior rounds used 4-8 B/lane and plateaued at ~4.2 TB/s).
//  - TPB=128, thread owns 4 adjacent cols (c0=4t): float4 loads AND stores.
//  - 12-deep register ring (rows Y-5..Y+6), static shift-by-2; TWO rows per
//    phase share the ring (rows Y,Y+1 chains overlap on rr[1..10]) -> no
//    duplicate global loads; 2 float4 loads + 2 float4 stores per phase.
//  - mv in mod-4 residue-split float2 LDS (entry = (rowY,rowY+1) pair):
//    every access lane-stride 8B = free 2-way aliasing; 14 ds_read_b64 per
//    thread per phase for 8 pixels. One barrier per phase (16/block).
//  - horizontal taps via flat ascending scan m=0..13 (chain j uses m=j..j+10,
//    ascending) -> per-chain order unchanged -> bit-exact.
//  - no launch-bound clamp / NT stores / XCD swizzle (R7/R5/R10 lessons).

constexpr int W   = 512;
constexpr int H   = 512;
constexpr int PAD = 5;
constexpr int KS  = 11;
constexpr int TPB = 128;          // 4 cols per thread
constexpr int RPB = 32;           // output rows per block
constexpr int NPH = RPB / 2;      // 16 phases, 2 rows each

typedef float f32x4 __attribute__((ext_vector_type(4)));

__global__ __launch_bounds__(TPB)
void AdaptiveThresholding_57904749085171_kernel(const float* __restrict__ x,
                                                float* __restrict__ out)
{
    // q[buf][residue][entry]: padded col p -> q[buf][p&3][p>>2]; .x=row Y, .y=row Y+1
    __shared__ float2 q[2][4][132];   // 8.4 KB

    const int t  = (int)threadIdx.x;
    const int c0 = 4 * t;
    const int y0 = (int)blockIdx.x * RPB;
    const size_t ioff = (size_t)blockIdx.y * (size_t)(W * H);
    const float* __restrict__ xi = x + ioff;
    float* __restrict__ oi = out + ioff;
    const float wv = (float)(1.0 / 11.0);

    // Ring slot d holds virtual row Ybase-5+d for this thread's 4 cols.
    float rr[12][4];

    // ---- prologue: virtual rows y0-5 .. y0+4 -> slots 0..9 ----
    #pragma unroll
    for (int d = 0; d < 10; ++d) {
        int j = y0 - PAD + d;
        int src = j < 0 ? 0 : (j >= H ? H - 1 : j);
        const f32x4 v = *(const f32x4*)(xi + (size_t)src * W + c0);
        #pragma unroll
        for (int jj = 0; jj < 4; ++jj) rr[d][jj] = v[jj];
    }
    // depth-1 preload of rows y0+5, y0+6
    f32x4 pa, pb;
    {
        int ja = y0 + 5;  int sa = ja >= H ? H - 1 : ja;
        int jb = y0 + 6;  int sb = jb >= H ? H - 1 : jb;
        pa = *(const f32x4*)(xi + (size_t)sa * W + c0);
        pb = *(const f32x4*)(xi + (size_t)sb * W + c0);
    }

    for (int k = 0; k < NPH; ++k) {
        const int Y = y0 + 2 * k;

        // ---- complete ring: slots 10,11 = rows Y+5, Y+6 ----
        #pragma unroll
        for (int jj = 0; jj < 4; ++jj) { rr[10][jj] = pa[jj]; rr[11][jj] = pb[jj]; }

        // ---- issue preload for next phase (rows Y+7, Y+8, clamped) ----
        if (k + 1 < NPH) {
            int ja = Y + 7;  int sa = ja >= H ? H - 1 : ja;
            int jb = Y + 8;  int sb = jb >= H ? H - 1 : jb;
            pa = *(const f32x4*)(xi + (size_t)sa * W + c0);
            pb = *(const f32x4*)(xi + (size_t)sb * W + c0);
        }

        // ---- vertical f32 FMA chains, ascending row order ----
        // row Y: taps rr[0..10]; row Y+1: taps rr[1..11]
        float aE[4], aO[4];
        #pragma unroll
        for (int jj = 0; jj < 4; ++jj) {
            float s0 = 0.0f;
            #pragma unroll
            for (int d = 0; d < KS; ++d) s0 = fmaf(rr[d][jj], wv, s0);
            aE[jj] = s0;
            float s1 = 0.0f;
            #pragma unroll
            for (int d = 1; d < KS + 1; ++d) s1 = fmaf(rr[d][jj], wv, s1);
            aO[jj] = s1;
        }

        const int pp = k & 1;
        // own cols' padded indices p = 4t+5..4t+8 -> (r,i):
        q[pp][1][t + 1] = make_float2(aE[0], aO[0]);   // p=4t+5
        q[pp][2][t + 1] = make_float2(aE[1], aO[1]);   // p=4t+6
        q[pp][3][t + 1] = make_float2(aE[2], aO[2]);   // p=4t+7
        q[pp][0][t + 2] = make_float2(aE[3], aO[3]);   // p=4t+8
        if (t == 0) {                       // padded 0..4 = col-0 mv
            const float2 e = make_float2(aE[0], aO[0]);
            q[pp][0][0] = e; q[pp][1][0] = e; q[pp][2][0] = e; q[pp][3][0] = e;
            q[pp][0][1] = e;
        } else if (t == TPB - 1) {          // padded 517..521 = col-511 mv
            const float2 e = make_float2(aE[3], aO[3]);
            q[pp][1][129] = e; q[pp][2][129] = e; q[pp][3][129] = e;
            q[pp][0][130] = e; q[pp][1][130] = e;
        }

        // center values (rows Y, Y+1) before shifting
        float xE[4], xO[4];
        #pragma unroll
        for (int jj = 0; jj < 4; ++jj) { xE[jj] = rr[5][jj]; xO[jj] = rr[6][jj]; }

        // ---- shift ring by 2 (static indices) ----
        #pragma unroll
        for (int d = 0; d < 10; ++d)
            #pragma unroll
            for (int jj = 0; jj < 4; ++jj) rr[d][jj] = rr[d + 2][jj];

        __syncthreads();   // q[pp] visible; q[pp] rewritten only at phase k+2

        // ---- horizontal chains: flat ascending scan over 14 taps ----
        // tap m -> padded p = 4t+m -> q[pp][m&3][t+(m>>2)]; chain j uses m=j..j+10
        float mE[4] = {0.f, 0.f, 0.f, 0.f};
        float mO[4] = {0.f, 0.f, 0.f, 0.f};
        #pragma unroll
        for (int m = 0; m < 14; ++m) {
            const float2 v = q[pp][m & 3][t + (m >> 2)];
            #pragma unroll
            for (int jj = 0; jj < 4; ++jj) {
                if (m >= jj && m <= jj + 10) {
                    mE[jj] = fmaf(v.x, wv, mE[jj]);
                    mO[jj] = fmaf(v.y, wv, mO[jj]);
                }
            }
        }

        // ---- decisions + float4 stores (16 B/lane) ----
        f32x4 oE, oO;
        #pragma unroll
        for (int jj = 0; jj < 4; ++jj) {
            oE[jj] = (xE[jj] > mE[jj] - 2.0f) ? 0.0f : 255.0f;
            oO[jj] = (xO[jj] > mO[jj] - 2.0f) ? 0.0f : 255.0f;
        }
        *(f32x4*)(oi + (size_t)Y * W + c0)       = oE;
        *(f32x4*)(oi + (size_t)(Y + 1) * W + c0) = oO;
    }
}

extern "C" void kernel_launch(void* const* d_in, const int* in_sizes, int n_in,
                              void* d_out, int out_size, void* d_ws, size_t ws_size,
                              hipStream_t stream)
{
    const float* x = (const float*)d_in[0];
    float* out = (float*)d_out;
    const int n_imgs = in_sizes[0] / (W * H);   // 128

    dim3 grid(H / RPB, n_imgs);   // 16 x 128 = 2048 blocks
    dim3 block(TPB);
    AdaptiveThresholding_57904749085171_kernel<<<grid, block, 0, stream>>>(x, out);
}

// Round 14
// 59.940 us; speedup vs baseline: 1.0058x; 1.0058x over previous
//
#include <hip/hip_runtime.h>

// Adaptive mean thresholding: out = (x > mean11x11(x) - 2) ? 0 : 255, replicate border.
// BIT-EXACT contract (verified absmax=0.0 rounds 3-13): vertical 11-tap f32 FMA
// chain (ascending row order, weight (float)(1.0/11.0)), rounded to f32; then
// horizontal 11-tap f32 FMA chain (ascending col order); thresh = m - 2.0f;
// decision x > thresh. Replicate-border mv values are bitwise duplicates of the
// edge col's chain (synthesized by duplication, never recomputed).
//
// R14: the one untried {traffic x occupancy} cell.
//  - R11 (RPB=64): lowest FETCH (74.5 MB, halo amp 1.16x) but 16 waves/CU.
//  - R8/R12 (RPB=32): 24+ waves/CU but 85 MB FETCH.
//  - R14 = RPB=64 AND TPB=512 (one col/thread): 1024 blocks x 8 waves
//    = 32 waves/CU cap -> max occupancy + min halo traffic simultaneously.
//  - R8-proven skeleton: 11-deep register ring (static shift), double-buffered
//    mv row, 1 barrier/row, lane-consecutive LDS (0 conflicts), depth-1
//    preload, dynamic row loop (VGPR ~24).
//  - no launch-bound clamp / NT stores / XCD swizzle (R7/R5/R10 lessons).

constexpr int W   = 512;
constexpr int H   = 512;
constexpr int PAD = 5;            // (11-1)/2
constexpr int KS  = 11;
constexpr int TPB = 512;          // one column per thread
constexpr int RPB = 64;           // output rows per block (halo amp 74/64 = 1.16x)
constexpr int WP  = W + 2 * PAD;  // 522 padded columns

__global__ __launch_bounds__(TPB)
void AdaptiveThresholding_57904749085171_kernel(const float* __restrict__ x,
                                                float* __restrict__ out)
{
    __shared__ float mv[2][WP];    // double-buffered vertical-pass row (4.2 KB)

    const int t  = (int)threadIdx.x;       // owned column, 0..511
    const int y0 = (int)blockIdx.x * RPB;
    const size_t ioff = (size_t)blockIdx.y * (size_t)(W * H);
    const float* __restrict__ xi = x + ioff;
    float* __restrict__ oi = out + ioff;
    const float wv = (float)(1.0 / 11.0);

    // Register ring: rows y-5 .. y+5 for this thread's column (static indices).
    float r[KS];

    // ---- prologue: virtual rows y0-5 .. y0+4 -> r[0..9] ----
    #pragma unroll
    for (int k = 0; k < KS - 1; ++k) {
        int j = y0 - PAD + k;
        int src = j < 0 ? 0 : (j >= H ? H - 1 : j);
        r[k] = xi[(size_t)src * W + t];
    }
    // preload virtual row y0+5
    float p;
    {
        int j = y0 + PAD;
        int src = j >= H ? H - 1 : j;
        p = xi[(size_t)src * W + t];
    }

    for (int y = y0; y < y0 + RPB; ++y) {
        // complete the ring: r[10] = row y+5 (preloaded last iteration)
        r[KS - 1] = p;

        // ---- issue preload of next raw row early (latency cover) ----
        if (y + 1 < y0 + RPB) {
            int j = y + 1 + PAD;
            int src = j >= H ? H - 1 : j;
            p = xi[(size_t)src * W + t];
        }

        // ---- vertical f32 FMA chain (ascending row order) ----
        float a = 0.0f;
        #pragma unroll
        for (int d = 0; d < KS; ++d) a = fmaf(r[d], wv, a);

        const int pp = (y - y0) & 1;
        mv[pp][PAD + t] = a;                   // lane-consecutive: conflict-free
        if (t == 0) {
            #pragma unroll
            for (int i = 0; i < PAD; ++i) mv[pp][i] = a;           // == col-0 mv
        } else if (t == TPB - 1) {
            #pragma unroll
            for (int i = 0; i < PAD; ++i) mv[pp][W + PAD + i] = a; // == col-511 mv
        }

        // center row value (row y) before shifting
        const float xv = r[PAD];

        // ---- shift ring (static indices) ----
        #pragma unroll
        for (int d = 0; d < KS - 1; ++d) r[d] = r[d + 1];

        __syncthreads();   // mv[pp] visible to all waves

        // ---- horizontal f32 FMA chain (ascending col order) + decision ----
        float m = 0.0f;
        #pragma unroll
        for (int e = 0; e < KS; ++e) m = fmaf(mv[pp][t + e], wv, m);

        oi[(size_t)y * W + t] = (xv > m - 2.0f) ? 0.0f : 255.0f;
        // one barrier per iter: next iter writes mv[pp^1]; mv[pp] is rewritten
        // only at iter y+2, after every thread has passed barrier(y+1).
    }
}

extern "C" void kernel_launch(void* const* d_in, const int* in_sizes, int n_in,
                              void* d_out, int out_size, void* d_ws, size_t ws_size,
                              hipStream_t stream)
{
    const float* x = (const float*)d_in[0];
    float* out = (float*)d_out;
    const int n_imgs = in_sizes[0] / (W * H);   // 128

    dim3 grid(H / RPB, n_imgs);   // 8 x 128 = 1024 blocks
    dim3 block(TPB);
    AdaptiveThresholding_57904749085171_kernel<<<grid, block, 0, stream>>>(x, out);
}

// Round 15
// 52.247 us; speedup vs baseline: 1.1539x; 1.1472x over previous
//
#include <hip/hip_runtime.h>

// Adaptive mean thresholding: out = (x > mean11x11(x) - 2) ? 0 : 255, replicate border.
// BIT-EXACT contract (verified absmax=0.0 rounds 3-14): vertical 11-tap f32 FMA
// chain (ascending row order, weight (float)(1.0/11.0)), rounded to f32; then
// horizontal 11-tap f32 FMA chain (ascending col order); thresh = m - 2.0f;
// decision x > thresh. Replicate-border mv values are bitwise duplicates of the
// edge col's chain (synthesized by duplication, never recomputed).
//
// FINAL = R9 (best measured: 52.0 us), restored verbatim.
// Session conclusion: 7 structures spanning occupancy 23-80%, VALU busy-time
// 24-45us, conflicts 0-6.5M, FETCH 74-106 MB, I/O width 4-16 B/lane all
// plateau at 52-56us = ~4.2 TB/s effective mixed-stream rate (input+output
// 265 MB > 256 MB L3, so fetch is partly HBM-irreducible). Memory-system
// roofline for this access pattern.

constexpr int W   = 512;
constexpr int H   = 512;
constexpr int PAD = 5;            // (11-1)/2
constexpr int KS  = 11;
constexpr int RS  = 12;           // ring slots (rows y-5 .. y+6)
constexpr int TPB = 256;          // cols t and t+256 per thread
constexpr int RPB = 32;           // output rows per block
constexpr int PH  = RPB / 2;      // 16 phases, 2 rows each
constexpr int WP  = W + 2 * PAD;  // 522 padded columns

__global__ __launch_bounds__(TPB)
void AdaptiveThresholding_57904749085171_kernel(const float* __restrict__ x,
                                                float* __restrict__ out)
{
    __shared__ float mvp[2][WP][2];   // [buf][padded col][row parity], 8.4 KB

    const int t  = (int)threadIdx.x;
    const int cA = t;
    const int cB = t + 256;
    const int y0 = (int)blockIdx.x * RPB;
    const size_t ioff = (size_t)blockIdx.y * (size_t)(W * H);
    const float* __restrict__ xi = x + ioff;
    float* __restrict__ oi = out + ioff;
    const float wv = (float)(1.0 / 11.0);

    // Ring: slot s holds virtual row v with (v - (y0-5)) mod 12 == s.
    float r0[RS], r1[RS];
    float p0a, p0b, p1a, p1b;   // preloaded next two virtual rows (cols A,B)

    // ---- prologue: virtual rows y0-5 .. y0+4 -> slots 0..9 ----
    #pragma unroll
    for (int j = 0; j < 10; ++j) {
        int v = y0 - PAD + j;
        int src = v < 0 ? 0 : (v >= H ? H - 1 : v);
        const float* rp = xi + (size_t)src * W;
        r0[j] = rp[cA];
        r1[j] = rp[cB];
    }
    {
        int v = y0 + 5;  int src = v >= H ? H - 1 : v;
        const float* rp = xi + (size_t)src * W;
        p0a = rp[cA]; p0b = rp[cB];
    }
    {
        int v = y0 + 6;  int src = v >= H ? H - 1 : v;
        const float* rp = xi + (size_t)src * W;
        p1a = rp[cA]; p1b = rp[cB];
    }

    #pragma unroll
    for (int k = 0; k < PH; ++k) {
        const int y = y0 + 2 * k;

        // ---- place preloaded rows y+5, y+6 into slots (2k+10)%12, (2k+11)%12 ----
        r0[(2 * k + 10) % RS] = p0a;  r1[(2 * k + 10) % RS] = p0b;
        r0[(2 * k + 11) % RS] = p1a;  r1[(2 * k + 11) % RS] = p1b;

        // ---- issue preload for the next phase (rows y+7, y+8, clamped) ----
        if (k + 1 < PH) {
            int v1 = y + 7;  int s1 = v1 >= H ? H - 1 : v1;
            int v2 = y + 8;  int s2 = v2 >= H ? H - 1 : v2;
            const float* rp1 = xi + (size_t)s1 * W;
            const float* rp2 = xi + (size_t)s2 * W;
            p0a = rp1[cA]; p0b = rp1[cB];
            p1a = rp2[cA]; p1b = rp2[cB];
        }

        // ---- vertical f32 FMA chains, ascending row order (4 independent) ----
        float aA0 = 0.0f, aB0 = 0.0f, aA1 = 0.0f, aB1 = 0.0f;
        #pragma unroll
        for (int d = 0; d < KS; ++d) {
            const int s = (2 * k + d) % RS;        // row y-5+d
            aA0 = fmaf(r0[s], wv, aA0);
            aB0 = fmaf(r1[s], wv, aB0);
        }
        #pragma unroll
        for (int d = 0; d < KS; ++d) {
            const int s = (2 * k + 1 + d) % RS;    // row y-4+d
            aA1 = fmaf(r0[s], wv, aA1);
            aB1 = fmaf(r1[s], wv, aB1);
        }

        const int pp = k & 1;
        *(float2*)&mvp[pp][PAD + cA][0] = make_float2(aA0, aA1);
        *(float2*)&mvp[pp][PAD + cB][0] = make_float2(aB0, aB1);
        if (t == 0) {
            #pragma unroll
            for (int i = 0; i < PAD; ++i)
                *(float2*)&mvp[pp][i][0] = make_float2(aA0, aA1);          // == col 0
        } else if (t == TPB - 1) {
            #pragma unroll
            for (int i = 0; i < PAD; ++i)
                *(float2*)&mvp[pp][W + PAD + i][0] = make_float2(aB0, aB1); // == col 511
        }

        // center values for rows y (slot 2k+5) and y+1 (slot 2k+6)
        const float xA0 = r0[(2 * k + 5) % RS], xB0 = r1[(2 * k + 5) % RS];
        const float xA1 = r0[(2 * k + 6) % RS], xB1 = r1[(2 * k + 6) % RS];

        __syncthreads();   // mvp[pp] visible; safe vs pp^1 writes (R4/R8 note)

        // ---- horizontal f32 FMA chains (ascending col order), b64 taps ----
        float mA0 = 0.0f, mA1 = 0.0f, mB0 = 0.0f, mB1 = 0.0f;
        #pragma unroll
        for (int e = 0; e < KS; ++e) {
            const float2 v = *(const float2*)&mvp[pp][cA + e][0];
            mA0 = fmaf(v.x, wv, mA0);
            mA1 = fmaf(v.y, wv, mA1);
        }
        #pragma unroll
        for (int e = 0; e < KS; ++e) {
            const float2 v = *(const float2*)&mvp[pp][cB + e][0];
            mB0 = fmaf(v.x, wv, mB0);
            mB1 = fmaf(v.y, wv, mB1);
        }

        float* opr0 = oi + (size_t)y * W;
        float* opr1 = oi + (size_t)(y + 1) * W;
        opr0[cA] = (xA0 > mA0 - 2.0f) ? 0.0f : 255.0f;
        opr0[cB] = (xB0 > mB0 - 2.0f) ? 0.0f : 255.0f;
        opr1[cA] = (xA1 > mA1 - 2.0f) ? 0.0f : 255.0f;
        opr1[cB] = (xB1 > mB1 - 2.0f) ? 0.0f : 255.0f;
    }
}

extern "C" void kernel_launch(void* const* d_in, const int* in_sizes, int n_in,
                              void* d_out, int out_size, void* d_ws, size_t ws_size,
                              hipStream_t stream)
{
    const float* x = (const float*)d_in[0];
    float* out = (float*)d_out;
    const int n_imgs = in_sizes[0] / (W * H);   // 128

    dim3 grid(H / RPB, n_imgs);   // 16 x 128 = 2048 blocks
    dim3 block(TPB);
    AdaptiveThresholding_57904749085171_kernel<<<grid, block, 0, stream>>>(x, out);
}